// Round 2
// baseline (311.336 us; speedup 1.0000x reference)
//
#include <hip/hip_runtime.h>
#include <stdint.h>

// LSTM autoencoder B=32768 T=30 I=4 H=64 L=32, fp32 in/out.
// v15 = fully FUSED per-wave design (replaces the 2-role cross-wave pipeline):
// each wave owns 16 batches end-to-end (enc1->enc2->dec1->dec2). All layer
// handoffs are same-wave LDS images (in-order per-wave DS + wave_barrier,
// the mechanism v14 already used for h2b) -> the 62 __syncthreads of the
// lockstep pipeline collapse to 3 (staging + enc->dec restage). 8 waves x
// 16 batches = 128 batches/block, grid 256, 2 waves/SIMD (weights pin LDS).
// Work per SIMD is conserved and perfectly balanced by construction.
// Enabling changes vs v14:
//  - fold tile (16KB, half zeros) -> 4KB compact W1c rows [whi x4 | wlo x4];
//    A-frag = [p0,p1,p0,p1] for ALL quads (k12-31 garbage is harmless: the
//    x B-frag is zero there). enc1 bias moves to fp32 C-init reads (b1f),
//    like enc2/dec1 already do.
//  - h1/h3 single-buffered (producer==consumer, in-order DS).
// Math/quantization identical to v14: 1-term bf16 h, 2-term x (hi+lo),
// log2e folded into weights (g-gate rows 2*log2e), unitH = 5 exp2 + 2 rcp.
// Layouts (HW-verified): C/D col=lane&15(batch), row=(lane>>4)*4+reg(unit)
// [m89]; A/B m|n=lane&15, k=(lane>>4)*8+j [m120].

typedef unsigned short u16;
typedef unsigned int u32;
typedef __attribute__((ext_vector_type(8))) short bf16x8;
typedef __attribute__((ext_vector_type(4))) float f32x4;
typedef __attribute__((ext_vector_type(4))) u32 u32x4;
typedef __attribute__((ext_vector_type(2))) u32 u32x2;

#define BATCH 32768
#define TT 30
#define IN 4
#define WAVES 8
#define BLOCKT (WAVES * 64)   // 512
#define MB 16
#define BPB (WAVES * MB)      // 128 batches/block -> grid 256

#define LOG2E 1.4426950408889634f
#define LOG2E2 2.8853900817779268f

// ---- LDS word (u32/float) offsets ----
// enc weights (region 0..15359)
#define O_WHH1 0        // 8192 words (32 frags)
#define O_W1C  8192     // 1024 words (256 rows x 8 u16: whi0-3 | wlo0-3)
#define O_WIH2 9216     // 4096
#define O_WHH2 13312    // 2048 -> 15360
// dec weights (same region, restaged)
#define O_WHH3 0        // 8192
#define O_WIH3 8192     // 4096
#define O_WIH4 12288    // 512
#define O_W4HHF 12800   // 64 fp32 -> 12864
// biases (outside W region, staged once, survive the restage)
#define O_B1F 15360     // 256
#define O_B2F 15616     // 128
#define O_B3F 15744     // 256
#define O_B4F 16000     // 16
#define O_BUFS 16016
// per-wave bufs: h1/h3 image 512w | h2/latent 256w | gbuf 256w | h4 64w
#define PBUF 1088
#define SMEM_WORDS (O_BUFS + WAVES * PBUF)   // 24720
#define SMEM_BYTES (SMEM_WORDS * 4)          // 98880 <= 163840

#define WB() __builtin_amdgcn_wave_barrier()
// arg order: A = weight frag, B = data frag.
#define MFMA(a, b, c) __builtin_amdgcn_mfma_f32_16x16x32_bf16((a), (b), (c), 0, 0, 0)

__device__ __forceinline__ u16 f2bf(float f) {   // RNE fp32->bf16 (staging)
    u32 u = __float_as_uint(f);
    u += 0x7fffu + ((u >> 16) & 1u);
    return (u16)(u >> 16);
}
__device__ __forceinline__ float bf2f(u16 v) { return __uint_as_float(((u32)v) << 16); }

// packed RNE fp32x2 -> bf16x2 (lo=a, hi=b)
__device__ __forceinline__ u32 cvtpk2(float a, float b) {
    u32 d;
    asm("v_cvt_pk_bf16_f32 %0, %1, %2" : "=v"(d) : "v"(a), "v"(b));
    return d;
}

// Fused LSTM cell update. Inputs pre-scaled (i,f,o by log2e; g by 2*log2e).
// Exact algebra of sig/tanh with merged reciprocals: 5 exp2 + 2 rcp.
__device__ __forceinline__ float unitH(float yi, float yf, float yg, float yo, float& c) {
    const float ei = __builtin_amdgcn_exp2f(-yi);
    const float ef = __builtin_amdgcn_exp2f(-yf);
    const float eg = __builtin_amdgcn_exp2f(yg);
    const float eo = __builtin_amdgcn_exp2f(-yo);
    const float Z = (1.f + ei) * (1.f + eg);
    const float X = 1.f + ef;
    const float num = fmaf(eg - 1.f, X, c * Z);
    c = num * __builtin_amdgcn_rcpf(X * Z);
    const float ec = __builtin_amdgcn_exp2f(c * LOG2E2);
    return (ec - 1.f) * __builtin_amdgcn_rcpf((1.f + eo) * (1.f + ec));
}

// Stage fp32 W[N][K] -> bf16 hi, operand-fragment order, rows pre-scaled by
// gate factor (gate = (n>>GS)&3; g-gate (==2) gets 2*log2e, else log2e).
template <int KT, int GS>
__device__ __forceinline__ void stageBh(u16* hi, const float* src, int N, int tid) {
    const int K = KT * 32;
    const int total = N * K;
    for (int idx = tid; idx < total; idx += BLOCKT) {
        const int j = idx & 7;
        const int l = (idx >> 3) & 63;
        const int pr = idx >> 9;
        const int kt = pr & (KT - 1);
        const int nt = pr / KT;
        const int n = (nt << 4) | (l & 15);
        const int k = (kt << 5) + ((l >> 4) << 3) + j;
        const float s = (((n >> GS) & 3) == 2) ? LOG2E2 : LOG2E;
        hi[idx] = f2bf(src[n * K + k] * s);
    }
}

__global__ __launch_bounds__(BLOCKT)
__attribute__((amdgpu_waves_per_eu(2)))
void lstm_ae(
    const float* __restrict__ x,
    const float* __restrict__ w1ih, const float* __restrict__ w1hh,
    const float* __restrict__ b1i, const float* __restrict__ b1h,
    const float* __restrict__ w2ih, const float* __restrict__ w2hh,
    const float* __restrict__ b2i, const float* __restrict__ b2h,
    const float* __restrict__ w3ih, const float* __restrict__ w3hh,
    const float* __restrict__ b3i, const float* __restrict__ b3h,
    const float* __restrict__ w4ih, const float* __restrict__ w4hh,
    const float* __restrict__ b4i, const float* __restrict__ b4h,
    float* __restrict__ out) {
    extern __shared__ float smem[];
    float* W = smem;

    const int tid = threadIdx.x;
    const int wave = tid >> 6, lane = tid & 63;
    const int col = lane & 15, quad = lane >> 4;

    float* pb = smem + O_BUFS + wave * PBUF;
    u16* h1b = (u16*)pb;            // 1024 u16: h1 (enc) / h3 (dec) image
    u16* h2b = (u16*)(pb + 512);    // 512 u16: h2 / latent
    float* gbuf = pb + 768;         // 256 f (dec2 gate shuffle)
    float* bufH4 = pb + 1024;       // 64 f (dec2 h feedback)

    const int b0w = blockIdx.x * BPB + wave * MB;
    // per-lane u16 base of this lane's 4-unit group inside a k-tile frag
    const int hbase = (col << 3) + ((quad & 1) << 2) + ((quad >> 1) << 7);

    // ---------------- stage ENCODER weights + ALL biases ----------------
    stageBh<2, 6>((u16*)(W + O_WHH1), w1hh, 256, tid);
    stageBh<2, 5>((u16*)(W + O_WIH2), w2ih, 128, tid);
    stageBh<1, 5>((u16*)(W + O_WHH2), w2hh, 128, tid);
    {   // compact W1ih tile: row n = [whi0..3, wlo0..3]
        u16* C = (u16*)(W + O_W1C);
        for (int idx = tid; idx < 2048; idx += BLOCKT) {
            const int n = idx >> 3, j = idx & 7;
            const float sc = ((n >> 6) == 2) ? LOG2E2 : LOG2E;
            const float w = w1ih[n * 4 + (j & 3)] * sc;
            C[idx] = (j < 4) ? f2bf(w) : f2bf(w - bf2f(f2bf(w)));
        }
    }
    float* b1f = W + O_B1F;
    float* b2f = W + O_B2F;
    float* b3f = W + O_B3F;
    float* b4f = W + O_B4F;
    for (int i = tid; i < 256; i += BLOCKT)
        b1f[i] = (b1i[i] + b1h[i]) * (((i >> 6) == 2) ? LOG2E2 : LOG2E);
    for (int i = tid; i < 128; i += BLOCKT)
        b2f[i] = (b2i[i] + b2h[i]) * (((i >> 5) == 2) ? LOG2E2 : LOG2E);
    for (int i = tid; i < 256; i += BLOCKT)
        b3f[i] = (b3i[i] + b3h[i]) * (((i >> 6) == 2) ? LOG2E2 : LOG2E);
    for (int i = tid; i < 16; i += BLOCKT)
        b4f[i] = (b4i[i] + b4h[i]) * (((i >> 2) == 2) ? LOG2E2 : LOG2E);
    {   // zero own h1 + h2 images
        u32* z = (u32*)pb;
        for (int i = lane; i < 768; i += 64) z[i] = 0u;
    }
    __syncthreads();

    const u16* Whh1hi = (const u16*)(W + O_WHH1);
    const u16* Wih2hi = (const u16*)(W + O_WIH2);
    const u16* Whh2hi = (const u16*)(W + O_WHH2);
    const u16* W1cL = (const u16*)(W + O_W1C) + (col << 3) + ((quad == 1) ? 4 : 0);

    // ================= encoder (fused, no barriers) =================
    // c-state mapping: c[q][r] <-> (batch=col, unit=q*16+quad*4+r)
    float c1[4][4];
    float c2[2][4];
#pragma unroll
    for (int q = 0; q < 4; ++q)
#pragma unroll
        for (int r = 0; r < 4; ++r) c1[q][r] = 0.f;
#pragma unroll
    for (int q = 0; q < 2; ++q)
#pragma unroll
        for (int r = 0; r < 4; ++r) c2[q][r] = 0.f;

    float4 xcur = *reinterpret_cast<const float4*>(x + ((size_t)(b0w + col) * TT + 0) * IN);

    for (int s = 0; s < TT; ++s) {
        // ---- enc1 for t=s ----
        // x B-frag in regs: quad0 [xhi,xlo], quad1 [xhi,0], quad2/3 0.
        const u32 hi01 = cvtpk2(xcur.x, xcur.y);
        const u32 hi23 = cvtpk2(xcur.z, xcur.w);
        const float r0 = xcur.x - __uint_as_float(hi01 << 16);
        const float r1 = xcur.y - __uint_as_float(hi01 & 0xffff0000u);
        const float r2 = xcur.z - __uint_as_float(hi23 << 16);
        const float r3 = xcur.w - __uint_as_float(hi23 & 0xffff0000u);
        const u32 lo01 = cvtpk2(r0, r1);
        const u32 lo23 = cvtpk2(r2, r3);
        u32x4 xv;
        xv.x = (quad <= 1) ? hi01 : 0u;
        xv.y = (quad <= 1) ? hi23 : 0u;
        xv.z = (quad == 0) ? lo01 : 0u;
        xv.w = (quad == 0) ? lo23 : 0u;
        const bf16x8 a1x = __builtin_bit_cast(bf16x8, xv);
        {   // prefetch next x
            const int tn = (s + 1 < TT) ? s + 1 : s;
            xcur = *reinterpret_cast<const float4*>(x + ((size_t)(b0w + col) * TT + tn) * IN);
        }
        const bf16x8 a1h0 = *reinterpret_cast<const bf16x8*>(h1b + lane * 8);        // h1[s-1]
        const bf16x8 a1h1 = *reinterpret_cast<const bf16x8*>(h1b + (64 + lane) * 8);
#pragma unroll
        for (int q = 0; q < 4; ++q) {
            f32x4 acc[4];
#pragma unroll
            for (int i = 0; i < 4; ++i) {
                const int nt = i * 4 + q;
                const u32x2 wp = *reinterpret_cast<const u32x2*>(W1cL + nt * 128);
                u32x4 afu;
                afu.x = wp.x; afu.y = wp.y; afu.z = wp.x; afu.w = wp.y;
                const bf16x8 af = __builtin_bit_cast(bf16x8, afu);
                const bf16x8 bh0 = *reinterpret_cast<const bf16x8*>(Whh1hi + ((nt * 2 + 0) * 64 + lane) * 8);
                const bf16x8 bh1 = *reinterpret_cast<const bf16x8*>(Whh1hi + ((nt * 2 + 1) * 64 + lane) * 8);
                f32x4 a = *reinterpret_cast<const f32x4*>(b1f + nt * 16 + (quad << 2));
                a = MFMA(af, a1x, a);
                a = MFMA(bh0, a1h0, a);
                a = MFMA(bh1, a1h1, a);
                acc[i] = a;
            }
            const float h0 = unitH(acc[0][0], acc[1][0], acc[2][0], acc[3][0], c1[q][0]);
            const float h1 = unitH(acc[0][1], acc[1][1], acc[2][1], acc[3][1], c1[q][1]);
            const float h2 = unitH(acc[0][2], acc[1][2], acc[2][2], acc[3][2], c1[q][2]);
            const float h3 = unitH(acc[0][3], acc[1][3], acc[2][3], acc[3][3], c1[q][3]);
            u32x2 wv;
            wv.x = cvtpk2(h0, h1);
            wv.y = cvtpk2(h2, h3);
            *reinterpret_cast<u32x2*>(h1b + hbase + ((q >> 1) << 9) + ((q & 1) << 8)) = wv;
        }
        WB();
        // ---- enc2 for t=s (same wave, h1[s] just written) ----
        const bf16x8 e1h0 = *reinterpret_cast<const bf16x8*>(h1b + lane * 8);
        const bf16x8 e1h1 = *reinterpret_cast<const bf16x8*>(h1b + (64 + lane) * 8);
        const bf16x8 a2h = *reinterpret_cast<const bf16x8*>(h2b + lane * 8);         // h2[s-1]
        f32x4 acc2[8];
#pragma unroll
        for (int nt = 0; nt < 8; ++nt) {
            const bf16x8 bh0 = *reinterpret_cast<const bf16x8*>(Wih2hi + ((nt * 2 + 0) * 64 + lane) * 8);
            const bf16x8 bh1 = *reinterpret_cast<const bf16x8*>(Wih2hi + ((nt * 2 + 1) * 64 + lane) * 8);
            const bf16x8 ch = *reinterpret_cast<const bf16x8*>(Whh2hi + (nt * 64 + lane) * 8);
            f32x4 a = *reinterpret_cast<const f32x4*>(b2f + nt * 16 + (quad << 2));
            a = MFMA(bh0, e1h0, a);
            a = MFMA(bh1, e1h1, a);
            a = MFMA(ch, a2h, a);
            acc2[nt] = a;
        }
        WB();   // a2h read before h2 overwrite (in-order per-wave DS)
#pragma unroll
        for (int q = 0; q < 2; ++q) {
            const float h0 = unitH(acc2[q][0], acc2[2 + q][0], acc2[4 + q][0], acc2[6 + q][0], c2[q][0]);
            const float h1 = unitH(acc2[q][1], acc2[2 + q][1], acc2[4 + q][1], acc2[6 + q][1], c2[q][1]);
            const float h2 = unitH(acc2[q][2], acc2[2 + q][2], acc2[4 + q][2], acc2[6 + q][2], c2[q][2]);
            const float h3 = unitH(acc2[q][3], acc2[2 + q][3], acc2[4 + q][3], acc2[6 + q][3], c2[q][3]);
            u32x2 wv;
            wv.x = cvtpk2(h0, h1);
            wv.y = cvtpk2(h2, h3);
            *reinterpret_cast<u32x2*>(h2b + hbase + (q << 8)) = wv;
        }
        WB();
    }
    // h2b holds the latent.

    // ---------------- re-stage DECODER weights ----------------
    __syncthreads();   // all waves done reading enc weights
    stageBh<2, 6>((u16*)(W + O_WHH3), w3hh, 256, tid);
    stageBh<1, 6>((u16*)(W + O_WIH3), w3ih, 256, tid);
    stageBh<2, 2>((u16*)(W + O_WIH4), w4ih, 16, tid);
    for (int i = tid; i < 64; i += BLOCKT)
        W[O_W4HHF + i] = w4hh[i] * ((((i >> 4) & 3) == 2) ? LOG2E2 : LOG2E);

    // own-wave: latent frag to regs, zero h3 image + h4, init states
    const bf16x8 aLh = *reinterpret_cast<const bf16x8*>(h2b + lane * 8);
    {
        u32* z = (u32*)pb;
        for (int i = lane; i < 512; i += 64) z[i] = 0u;   // h3
        bufH4[lane] = 0.f;
    }
    float c3[4][4];
#pragma unroll
    for (int q = 0; q < 4; ++q)
#pragma unroll
        for (int r = 0; r < 4; ++r) c3[q][r] = 0.f;
    float c4 = 0.f;
    const f32x4 bias4v = *reinterpret_cast<const f32x4*>(b4f + (quad << 2));
    const int u4 = lane & 3, mb = lane >> 2;
    __syncthreads();   // dec weights visible

    const u16* Whh3hi = (const u16*)(W + O_WHH3);
    const u16* Wih3hi = (const u16*)(W + O_WIH3);
    const u16* Wih4hi = (const u16*)(W + O_WIH4);
    const float* W4hhF = W + O_W4HHF;

    // ================= decoder (fused, no barriers) =================
    for (int s = 0; s < TT; ++s) {
        // ---- dec1 for t=s ----
        const bf16x8 a3h0 = *reinterpret_cast<const bf16x8*>(h1b + lane * 8);        // h3[s-1]
        const bf16x8 a3h1 = *reinterpret_cast<const bf16x8*>(h1b + (64 + lane) * 8);
#pragma unroll
        for (int q = 0; q < 4; ++q) {
            f32x4 acc[4];
#pragma unroll
            for (int i = 0; i < 4; ++i) {
                const int nt = i * 4 + q;
                const bf16x8 bL = *reinterpret_cast<const bf16x8*>(Wih3hi + (nt * 64 + lane) * 8);
                const bf16x8 bh0 = *reinterpret_cast<const bf16x8*>(Whh3hi + ((nt * 2 + 0) * 64 + lane) * 8);
                const bf16x8 bh1 = *reinterpret_cast<const bf16x8*>(Whh3hi + ((nt * 2 + 1) * 64 + lane) * 8);
                f32x4 a = *reinterpret_cast<const f32x4*>(b3f + nt * 16 + (quad << 2));
                a = MFMA(bL, aLh, a);
                a = MFMA(bh0, a3h0, a);
                a = MFMA(bh1, a3h1, a);
                acc[i] = a;
            }
            const float h0 = unitH(acc[0][0], acc[1][0], acc[2][0], acc[3][0], c3[q][0]);
            const float h1 = unitH(acc[0][1], acc[1][1], acc[2][1], acc[3][1], c3[q][1]);
            const float h2 = unitH(acc[0][2], acc[1][2], acc[2][2], acc[3][2], c3[q][2]);
            const float h3 = unitH(acc[0][3], acc[1][3], acc[2][3], acc[3][3], c3[q][3]);
            u32x2 wv;
            wv.x = cvtpk2(h0, h1);
            wv.y = cvtpk2(h2, h3);
            *reinterpret_cast<u32x2*>(h1b + hbase + ((q >> 1) << 9) + ((q & 1) << 8)) = wv;
        }
        WB();
        // ---- dec2 for t=s (same wave, h3[s] just written) ----
        const bf16x8 d3h0 = *reinterpret_cast<const bf16x8*>(h1b + lane * 8);
        const bf16x8 d3h1 = *reinterpret_cast<const bf16x8*>(h1b + (64 + lane) * 8);
        f32x4 acc4 = bias4v;
        {   // fp32 Whh4 part: gate rows n=quad*4+r, batch col
            const float4 hv = *reinterpret_cast<const float4*>(bufH4 + (col << 2));  // h4[s-1]
#pragma unroll
            for (int r = 0; r < 4; ++r) {
                const float4 w4 = *reinterpret_cast<const float4*>(W4hhF + ((quad * 4 + r) << 2));
                float sa = acc4[r];
                sa = fmaf(w4.x, hv.x, sa);
                sa = fmaf(w4.y, hv.y, sa);
                sa = fmaf(w4.z, hv.z, sa);
                sa = fmaf(w4.w, hv.w, sa);
                acc4[r] = sa;
            }
        }
        {
            const bf16x8 bh0 = *reinterpret_cast<const bf16x8*>(Wih4hi + (0 * 64 + lane) * 8);
            const bf16x8 bh1 = *reinterpret_cast<const bf16x8*>(Wih4hi + (1 * 64 + lane) * 8);
            acc4 = MFMA(bh0, d3h0, acc4);
            acc4 = MFMA(bh1, d3h1, acc4);
        }
        WB();
        // acc4[r] = gate row quad*4+r for batch col -> gbuf[batch][gaterow]
        *reinterpret_cast<f32x4*>(gbuf + (col << 4) + (quad << 2)) = acc4;
        WB();
        {   // epilogue: lane = (batch mb, unit u4)
            const float yi = gbuf[mb * 16 + u4];
            const float yf = gbuf[mb * 16 + 4 + u4];
            const float yg = gbuf[mb * 16 + 8 + u4];
            const float yo = gbuf[mb * 16 + 12 + u4];
            const float h = unitH(yi, yf, yg, yo, c4);
            out[((size_t)(b0w + mb) * TT + s) * IN + u4] = h;
            bufH4[mb * 4 + u4] = h;
        }
        WB();
    }
}

extern "C" void kernel_launch(void* const* d_in, const int* in_sizes, int n_in,
                              void* d_out, int out_size, void* d_ws, size_t ws_size,
                              hipStream_t stream) {
    (void)in_sizes; (void)n_in; (void)d_ws; (void)ws_size; (void)out_size;
    hipFuncSetAttribute(reinterpret_cast<const void*>(lstm_ae),
                        hipFuncAttributeMaxDynamicSharedMemorySize, SMEM_BYTES);
    const float* xi = (const float*)d_in[0];
    const float* w1ih = (const float*)d_in[1];
    const float* w1hh = (const float*)d_in[2];
    const float* b1i = (const float*)d_in[3];
    const float* b1h = (const float*)d_in[4];
    const float* w2ih = (const float*)d_in[5];
    const float* w2hh = (const float*)d_in[6];
    const float* b2i = (const float*)d_in[7];
    const float* b2h = (const float*)d_in[8];
    const float* w3ih = (const float*)d_in[9];
    const float* w3hh = (const float*)d_in[10];
    const float* b3i = (const float*)d_in[11];
    const float* b3h = (const float*)d_in[12];
    const float* w4ih = (const float*)d_in[13];
    const float* w4hh = (const float*)d_in[14];
    const float* b4i = (const float*)d_in[15];
    const float* b4h = (const float*)d_in[16];
    float* out = (float*)d_out;

    lstm_ae<<<dim3(BATCH / BPB), dim3(BLOCKT), SMEM_BYTES, stream>>>(
        xi, w1ih, w1hh, b1i, b1h, w2ih, w2hh, b2i, b2h,
        w3ih, w3hh, b3i, b3h, w4ih, w4hh, b4i, b4h, out);
}

// Round 3
// 299.233 us; speedup vs baseline: 1.0404x; 1.0404x over previous
//
#include <hip/hip_runtime.h>
#include <stdint.h>

// LSTM autoencoder B=32768 T=30 I=4 H=64 L=32, fp32 in/out.
// v16 = v15 (fused per-wave, 257us) + IN-WAVE DIAGONAL PIPELINING:
// enc1[t+1] and enc2[t] are mutually independent (both need only h1[t]) ->
// one scheduling region per step: read h1[t] frags once, issue enc2[t]'s 24
// MFMAs and enc1[t+1]'s 48 MFMAs + 24 independent unitH chains together.
// Same for dec1[t+1] || dec2[t]. This restores the ILP that v14's cross-wave
// pipeline had (v15 post-mortem: 57% VALUBusy, 43% idle-issue at 2 w/SIMD)
// while keeping v15's zero-barrier main loops.
//  - h1/h3 double-buffered (in-order per-wave DS = only ordering needed;
//    no WB in enc loop, 2 WB/iter in dec for the gbuf transpose only).
//  - prologue steps use zero-register h fragments (h[-1]=0): no h1 zeroing.
//  - VGPR budget at 2 waves/SIMD is 256; v15 used 92. Hoisted to regs:
//    b2 bias (8 f32x4), b3 bias (16 f32x4), Wih4 frags, W4hh rows, b4.
// Math/quantization identical: 1-term bf16 h, 2-term x, log2e in weights,
// unitH = 5 exp2 + 2 rcp. absmax pinned at fp32 floor 9.77e-4 since v4.
// Layouts (HW-verified): C/D col=lane&15(batch), row=(lane>>4)*4+reg(unit)
// [m89]; A/B m|n=lane&15, k=(lane>>4)*8+j [m120].

typedef unsigned short u16;
typedef unsigned int u32;
typedef __attribute__((ext_vector_type(8))) short bf16x8;
typedef __attribute__((ext_vector_type(4))) float f32x4;
typedef __attribute__((ext_vector_type(4))) u32 u32x4;
typedef __attribute__((ext_vector_type(2))) u32 u32x2;

#define BATCH 32768
#define TT 30
#define IN 4
#define WAVES 8
#define BLOCKT (WAVES * 64)   // 512
#define MB 16
#define BPB (WAVES * MB)      // 128 batches/block -> grid 256

#define LOG2E 1.4426950408889634f
#define LOG2E2 2.8853900817779268f

// ---- LDS word (u32/float) offsets ----
// enc weights (region 0..15359)
#define O_WHH1 0        // 8192 words (32 frags)
#define O_W1C  8192     // 1024 words (256 rows x 8 u16: whi0-3 | wlo0-3)
#define O_WIH2 9216     // 4096
#define O_WHH2 13312    // 2048 -> 15360
// dec weights (same region, restaged)
#define O_WHH3 0        // 8192
#define O_WIH3 8192     // 4096
#define O_WIH4 12288    // 512
#define O_W4HHF 12800   // 64 fp32 -> 12864
// biases (outside W region, staged once, survive the restage)
#define O_B1F 15360     // 256
#define O_B2F 15616     // 128
#define O_B3F 15744     // 256
#define O_B4F 16000     // 16
#define O_BUFS 16016
// per-wave bufs: h1/h3 DBUF 1024w (2 x 512) | h2/latent 256w | gbuf 256w | h4 64w
#define PBUF 1600
#define SMEM_WORDS (O_BUFS + WAVES * PBUF)   // 28816
#define SMEM_BYTES (SMEM_WORDS * 4)          // 115264 <= 163840

#define WB() __builtin_amdgcn_wave_barrier()
// arg order: A = weight frag, B = data frag.
#define MFMA(a, b, c) __builtin_amdgcn_mfma_f32_16x16x32_bf16((a), (b), (c), 0, 0, 0)

__device__ __forceinline__ u16 f2bf(float f) {   // RNE fp32->bf16 (staging)
    u32 u = __float_as_uint(f);
    u += 0x7fffu + ((u >> 16) & 1u);
    return (u16)(u >> 16);
}
__device__ __forceinline__ float bf2f(u16 v) { return __uint_as_float(((u32)v) << 16); }

// packed RNE fp32x2 -> bf16x2 (lo=a, hi=b)
__device__ __forceinline__ u32 cvtpk2(float a, float b) {
    u32 d;
    asm("v_cvt_pk_bf16_f32 %0, %1, %2" : "=v"(d) : "v"(a), "v"(b));
    return d;
}

// Fused LSTM cell update. Inputs pre-scaled (i,f,o by log2e; g by 2*log2e).
// Exact algebra of sig/tanh with merged reciprocals: 5 exp2 + 2 rcp.
__device__ __forceinline__ float unitH(float yi, float yf, float yg, float yo, float& c) {
    const float ei = __builtin_amdgcn_exp2f(-yi);
    const float ef = __builtin_amdgcn_exp2f(-yf);
    const float eg = __builtin_amdgcn_exp2f(yg);
    const float eo = __builtin_amdgcn_exp2f(-yo);
    const float Z = (1.f + ei) * (1.f + eg);
    const float X = 1.f + ef;
    const float num = fmaf(eg - 1.f, X, c * Z);
    c = num * __builtin_amdgcn_rcpf(X * Z);
    const float ec = __builtin_amdgcn_exp2f(c * LOG2E2);
    return (ec - 1.f) * __builtin_amdgcn_rcpf((1.f + eo) * (1.f + ec));
}

// Stage fp32 W[N][K] -> bf16 hi, operand-fragment order, rows pre-scaled by
// gate factor (gate = (n>>GS)&3; g-gate (==2) gets 2*log2e, else log2e).
template <int KT, int GS>
__device__ __forceinline__ void stageBh(u16* hi, const float* src, int N, int tid) {
    const int K = KT * 32;
    const int total = N * K;
    for (int idx = tid; idx < total; idx += BLOCKT) {
        const int j = idx & 7;
        const int l = (idx >> 3) & 63;
        const int pr = idx >> 9;
        const int kt = pr & (KT - 1);
        const int nt = pr / KT;
        const int n = (nt << 4) | (l & 15);
        const int k = (kt << 5) + ((l >> 4) << 3) + j;
        const float s = (((n >> GS) & 3) == 2) ? LOG2E2 : LOG2E;
        hi[idx] = f2bf(src[n * K + k] * s);
    }
}

__global__ __launch_bounds__(BLOCKT)
__attribute__((amdgpu_waves_per_eu(2)))
void lstm_ae(
    const float* __restrict__ x,
    const float* __restrict__ w1ih, const float* __restrict__ w1hh,
    const float* __restrict__ b1i, const float* __restrict__ b1h,
    const float* __restrict__ w2ih, const float* __restrict__ w2hh,
    const float* __restrict__ b2i, const float* __restrict__ b2h,
    const float* __restrict__ w3ih, const float* __restrict__ w3hh,
    const float* __restrict__ b3i, const float* __restrict__ b3h,
    const float* __restrict__ w4ih, const float* __restrict__ w4hh,
    const float* __restrict__ b4i, const float* __restrict__ b4h,
    float* __restrict__ out) {
    extern __shared__ float smem[];
    float* W = smem;

    const int tid = threadIdx.x;
    const int wave = tid >> 6, lane = tid & 63;
    const int col = lane & 15, quad = lane >> 4;

    float* pb = smem + O_BUFS + wave * PBUF;
    u16* h1d = (u16*)pb;            // 2048 u16: h1/h3 dbuf, parity p at p*1024
    u16* h2b = (u16*)(pb + 1024);   // 512 u16: h2 / latent
    float* gbuf = pb + 1280;        // 256 f (dec2 gate transpose)
    float* bufH4 = pb + 1536;       // 64 f (dec2 h feedback)

    const int b0w = blockIdx.x * BPB + wave * MB;
    // per-lane u16 base of this lane's 4-unit group inside a k-tile frag
    const int hbase = (col << 3) + ((quad & 1) << 2) + ((quad >> 1) << 7);

    // ---------------- stage ENCODER weights + ALL biases ----------------
    stageBh<2, 6>((u16*)(W + O_WHH1), w1hh, 256, tid);
    stageBh<2, 5>((u16*)(W + O_WIH2), w2ih, 128, tid);
    stageBh<1, 5>((u16*)(W + O_WHH2), w2hh, 128, tid);
    {   // compact W1ih tile: row n = [whi0..3, wlo0..3]
        u16* C = (u16*)(W + O_W1C);
        for (int idx = tid; idx < 2048; idx += BLOCKT) {
            const int n = idx >> 3, j = idx & 7;
            const float sc = ((n >> 6) == 2) ? LOG2E2 : LOG2E;
            const float w = w1ih[n * 4 + (j & 3)] * sc;
            C[idx] = (j < 4) ? f2bf(w) : f2bf(w - bf2f(f2bf(w)));
        }
    }
    float* b1f = W + O_B1F;
    float* b2f = W + O_B2F;
    float* b3f = W + O_B3F;
    float* b4f = W + O_B4F;
    for (int i = tid; i < 256; i += BLOCKT)
        b1f[i] = (b1i[i] + b1h[i]) * (((i >> 6) == 2) ? LOG2E2 : LOG2E);
    for (int i = tid; i < 128; i += BLOCKT)
        b2f[i] = (b2i[i] + b2h[i]) * (((i >> 5) == 2) ? LOG2E2 : LOG2E);
    for (int i = tid; i < 256; i += BLOCKT)
        b3f[i] = (b3i[i] + b3h[i]) * (((i >> 6) == 2) ? LOG2E2 : LOG2E);
    for (int i = tid; i < 16; i += BLOCKT)
        b4f[i] = (b4i[i] + b4h[i]) * (((i >> 2) == 2) ? LOG2E2 : LOG2E);
    {   // zero h2 + h4 feedback (h1/h3 need no zeroing: prologues use reg-0 frags)
        u32* z = (u32*)pb;
        for (int i = lane; i < 256; i += 64) z[1024 + i] = 0u;
        bufH4[lane] = 0.f;
    }
    __syncthreads();

    const u16* Whh1hi = (const u16*)(W + O_WHH1);
    const u16* Wih2hi = (const u16*)(W + O_WIH2);
    const u16* Whh2hi = (const u16*)(W + O_WHH2);
    const u16* W1cL = (const u16*)(W + O_W1C) + (col << 3) + ((quad == 1) ? 4 : 0);

    // hoist enc2 bias to regs (32 VGPR)
    f32x4 b2r[8];
#pragma unroll
    for (int nt = 0; nt < 8; ++nt)
        b2r[nt] = *reinterpret_cast<const f32x4*>(b2f + nt * 16 + (quad << 2));

    // ================= encoder (fused diagonal, no barriers) =================
    float c1[4][4];
    float c2[2][4];
#pragma unroll
    for (int q = 0; q < 4; ++q)
#pragma unroll
        for (int r = 0; r < 4; ++r) c1[q][r] = 0.f;
#pragma unroll
    for (int q = 0; q < 2; ++q)
#pragma unroll
        for (int r = 0; r < 4; ++r) c2[q][r] = 0.f;

    float4 xcur = *reinterpret_cast<const float4*>(x + ((size_t)(b0w + col) * TT + 0) * IN);

    // enc1 for timestep tnext, consuming h1[tnext-1] frags (ah0, ah1).
    auto enc1_step = [&](const bf16x8 ah0, const bf16x8 ah1, u16* hnext, int tnext) {
        const float4 xc = xcur;
        {   // prefetch next x
            const int tn = (tnext + 1 < TT) ? tnext + 1 : tnext;
            xcur = *reinterpret_cast<const float4*>(x + ((size_t)(b0w + col) * TT + tn) * IN);
        }
        // x B-frag in regs: quad0 [xhi,xlo], quad1 [xhi,0], quad2/3 0.
        const u32 hi01 = cvtpk2(xc.x, xc.y);
        const u32 hi23 = cvtpk2(xc.z, xc.w);
        const float r0 = xc.x - __uint_as_float(hi01 << 16);
        const float r1 = xc.y - __uint_as_float(hi01 & 0xffff0000u);
        const float r2 = xc.z - __uint_as_float(hi23 << 16);
        const float r3 = xc.w - __uint_as_float(hi23 & 0xffff0000u);
        const u32 lo01 = cvtpk2(r0, r1);
        const u32 lo23 = cvtpk2(r2, r3);
        u32x4 xv;
        xv.x = (quad <= 1) ? hi01 : 0u;
        xv.y = (quad <= 1) ? hi23 : 0u;
        xv.z = (quad == 0) ? lo01 : 0u;
        xv.w = (quad == 0) ? lo23 : 0u;
        const bf16x8 a1x = __builtin_bit_cast(bf16x8, xv);
#pragma unroll
        for (int q = 0; q < 4; ++q) {
            f32x4 acc[4];
#pragma unroll
            for (int i = 0; i < 4; ++i) {
                const int nt = i * 4 + q;
                const u32x2 wp = *reinterpret_cast<const u32x2*>(W1cL + nt * 128);
                u32x4 afu;
                afu.x = wp.x; afu.y = wp.y; afu.z = wp.x; afu.w = wp.y;
                const bf16x8 af = __builtin_bit_cast(bf16x8, afu);
                const bf16x8 bh0 = *reinterpret_cast<const bf16x8*>(Whh1hi + ((nt * 2 + 0) * 64 + lane) * 8);
                const bf16x8 bh1 = *reinterpret_cast<const bf16x8*>(Whh1hi + ((nt * 2 + 1) * 64 + lane) * 8);
                f32x4 a = *reinterpret_cast<const f32x4*>(b1f + nt * 16 + (quad << 2));
                a = MFMA(af, a1x, a);
                a = MFMA(bh0, ah0, a);
                a = MFMA(bh1, ah1, a);
                acc[i] = a;
            }
            const float h0 = unitH(acc[0][0], acc[1][0], acc[2][0], acc[3][0], c1[q][0]);
            const float h1 = unitH(acc[0][1], acc[1][1], acc[2][1], acc[3][1], c1[q][1]);
            const float h2 = unitH(acc[0][2], acc[1][2], acc[2][2], acc[3][2], c1[q][2]);
            const float h3 = unitH(acc[0][3], acc[1][3], acc[2][3], acc[3][3], c1[q][3]);
            u32x2 wv;
            wv.x = cvtpk2(h0, h1);
            wv.y = cvtpk2(h2, h3);
            *reinterpret_cast<u32x2*>(hnext + hbase + ((q >> 1) << 9) + ((q & 1) << 8)) = wv;
        }
    };

    {   // prologue: enc1[0] with h1[-1] = 0 (register zeros)
        const bf16x8 z8 = {};
        enc1_step(z8, z8, h1d, 0);   // writes h1[0] -> parity 0
    }
    for (int t = 0; t < TT - 1; ++t) {
        const u16* hcur = h1d + ((t & 1) << 10);          // h1[t]
        const bf16x8 ah0 = *reinterpret_cast<const bf16x8*>(hcur + lane * 8);
        const bf16x8 ah1 = *reinterpret_cast<const bf16x8*>(hcur + (64 + lane) * 8);
        // ---- enc2[t] MFMA head ----
        const bf16x8 a2h = *reinterpret_cast<const bf16x8*>(h2b + lane * 8);   // h2[t-1]
        f32x4 acc2[8];
#pragma unroll
        for (int nt = 0; nt < 8; ++nt) {
            const bf16x8 bh0 = *reinterpret_cast<const bf16x8*>(Wih2hi + ((nt * 2 + 0) * 64 + lane) * 8);
            const bf16x8 bh1 = *reinterpret_cast<const bf16x8*>(Wih2hi + ((nt * 2 + 1) * 64 + lane) * 8);
            const bf16x8 ch = *reinterpret_cast<const bf16x8*>(Whh2hi + (nt * 64 + lane) * 8);
            f32x4 a = b2r[nt];
            a = MFMA(bh0, ah0, a);
            a = MFMA(bh1, ah1, a);
            a = MFMA(ch, a2h, a);
            acc2[nt] = a;
        }
        // ---- enc1[t+1] (independent of enc2[t]: both only need h1[t]) ----
        enc1_step(ah0, ah1, h1d + (((t + 1) & 1) << 10), t + 1);
        // ---- enc2[t] tail ----
#pragma unroll
        for (int q = 0; q < 2; ++q) {
            const float h0 = unitH(acc2[q][0], acc2[2 + q][0], acc2[4 + q][0], acc2[6 + q][0], c2[q][0]);
            const float h1 = unitH(acc2[q][1], acc2[2 + q][1], acc2[4 + q][1], acc2[6 + q][1], c2[q][1]);
            const float h2 = unitH(acc2[q][2], acc2[2 + q][2], acc2[4 + q][2], acc2[6 + q][2], c2[q][2]);
            const float h3 = unitH(acc2[q][3], acc2[2 + q][3], acc2[4 + q][3], acc2[6 + q][3], c2[q][3]);
            u32x2 wv;
            wv.x = cvtpk2(h0, h1);
            wv.y = cvtpk2(h2, h3);
            *reinterpret_cast<u32x2*>(h2b + hbase + (q << 8)) = wv;
        }
    }
    {   // epilogue: enc2[TT-1]
        const u16* hcur = h1d + (((TT - 1) & 1) << 10);
        const bf16x8 ah0 = *reinterpret_cast<const bf16x8*>(hcur + lane * 8);
        const bf16x8 ah1 = *reinterpret_cast<const bf16x8*>(hcur + (64 + lane) * 8);
        const bf16x8 a2h = *reinterpret_cast<const bf16x8*>(h2b + lane * 8);
        f32x4 acc2[8];
#pragma unroll
        for (int nt = 0; nt < 8; ++nt) {
            const bf16x8 bh0 = *reinterpret_cast<const bf16x8*>(Wih2hi + ((nt * 2 + 0) * 64 + lane) * 8);
            const bf16x8 bh1 = *reinterpret_cast<const bf16x8*>(Wih2hi + ((nt * 2 + 1) * 64 + lane) * 8);
            const bf16x8 ch = *reinterpret_cast<const bf16x8*>(Whh2hi + (nt * 64 + lane) * 8);
            f32x4 a = b2r[nt];
            a = MFMA(bh0, ah0, a);
            a = MFMA(bh1, ah1, a);
            a = MFMA(ch, a2h, a);
            acc2[nt] = a;
        }
#pragma unroll
        for (int q = 0; q < 2; ++q) {
            const float h0 = unitH(acc2[q][0], acc2[2 + q][0], acc2[4 + q][0], acc2[6 + q][0], c2[q][0]);
            const float h1 = unitH(acc2[q][1], acc2[2 + q][1], acc2[4 + q][1], acc2[6 + q][1], c2[q][1]);
            const float h2 = unitH(acc2[q][2], acc2[2 + q][2], acc2[4 + q][2], acc2[6 + q][2], c2[q][2]);
            const float h3 = unitH(acc2[q][3], acc2[2 + q][3], acc2[4 + q][3], acc2[6 + q][3], c2[q][3]);
            u32x2 wv;
            wv.x = cvtpk2(h0, h1);
            wv.y = cvtpk2(h2, h3);
            *reinterpret_cast<u32x2*>(h2b + hbase + (q << 8)) = wv;
        }
    }
    // h2b holds the latent.

    // ---------------- re-stage DECODER weights ----------------
    __syncthreads();   // all waves done reading enc weights
    stageBh<2, 6>((u16*)(W + O_WHH3), w3hh, 256, tid);
    stageBh<1, 6>((u16*)(W + O_WIH3), w3ih, 256, tid);
    stageBh<2, 2>((u16*)(W + O_WIH4), w4ih, 16, tid);
    for (int i = tid; i < 64; i += BLOCKT)
        W[O_W4HHF + i] = w4hh[i] * ((((i >> 4) & 3) == 2) ? LOG2E2 : LOG2E);

    const bf16x8 aLh = *reinterpret_cast<const bf16x8*>(h2b + lane * 8);   // latent frag
    float c3[4][4];
#pragma unroll
    for (int q = 0; q < 4; ++q)
#pragma unroll
        for (int r = 0; r < 4; ++r) c3[q][r] = 0.f;
    float c4 = 0.f;
    const int u4 = lane & 3, mb = lane >> 2;
    __syncthreads();   // dec weights visible

    const u16* Whh3hi = (const u16*)(W + O_WHH3);
    const u16* Wih3hi = (const u16*)(W + O_WIH3);
    // hoist dec regs: b3 (64), b4 (4), Wih4 frags (8), W4hh rows (16)
    f32x4 b3r[16];
#pragma unroll
    for (int nt = 0; nt < 16; ++nt)
        b3r[nt] = *reinterpret_cast<const f32x4*>(b3f + nt * 16 + (quad << 2));
    const f32x4 bias4v = *reinterpret_cast<const f32x4*>(b4f + (quad << 2));
    const bf16x8 w4f0 = *reinterpret_cast<const bf16x8*>((const u16*)(W + O_WIH4) + (0 * 64 + lane) * 8);
    const bf16x8 w4f1 = *reinterpret_cast<const bf16x8*>((const u16*)(W + O_WIH4) + (1 * 64 + lane) * 8);
    float4 w4r[4];
#pragma unroll
    for (int r = 0; r < 4; ++r)
        w4r[r] = *reinterpret_cast<const float4*>(W + O_W4HHF + ((quad * 4 + r) << 2));

    // dec1 for timestep tnext, consuming h3[tnext-1] frags.
    auto dec1_step = [&](const bf16x8 ah0, const bf16x8 ah1, u16* hnext) {
#pragma unroll
        for (int q = 0; q < 4; ++q) {
            f32x4 acc[4];
#pragma unroll
            for (int i = 0; i < 4; ++i) {
                const int nt = i * 4 + q;
                const bf16x8 bL = *reinterpret_cast<const bf16x8*>(Wih3hi + (nt * 64 + lane) * 8);
                const bf16x8 bh0 = *reinterpret_cast<const bf16x8*>(Whh3hi + ((nt * 2 + 0) * 64 + lane) * 8);
                const bf16x8 bh1 = *reinterpret_cast<const bf16x8*>(Whh3hi + ((nt * 2 + 1) * 64 + lane) * 8);
                f32x4 a = MFMA(bL, aLh, b3r[nt]);
                a = MFMA(bh0, ah0, a);
                a = MFMA(bh1, ah1, a);
                acc[i] = a;
            }
            const float h0 = unitH(acc[0][0], acc[1][0], acc[2][0], acc[3][0], c3[q][0]);
            const float h1 = unitH(acc[0][1], acc[1][1], acc[2][1], acc[3][1], c3[q][1]);
            const float h2 = unitH(acc[0][2], acc[1][2], acc[2][2], acc[3][2], c3[q][2]);
            const float h3 = unitH(acc[0][3], acc[1][3], acc[2][3], acc[3][3], c3[q][3]);
            u32x2 wv;
            wv.x = cvtpk2(h0, h1);
            wv.y = cvtpk2(h2, h3);
            *reinterpret_cast<u32x2*>(hnext + hbase + ((q >> 1) << 9) + ((q & 1) << 8)) = wv;
        }
    };

    {   // prologue: dec1[0] with h3[-1] = 0
        const bf16x8 z8 = {};
        dec1_step(z8, z8, h1d);   // h3[0] -> parity 0
    }
    for (int t = 0; t < TT - 1; ++t) {
        const u16* hcur = h1d + ((t & 1) << 10);          // h3[t]
        const bf16x8 ah0 = *reinterpret_cast<const bf16x8*>(hcur + lane * 8);
        const bf16x8 ah1 = *reinterpret_cast<const bf16x8*>(hcur + (64 + lane) * 8);
        // ---- dec2[t] MFMA head ----
        f32x4 acc4 = bias4v;
        {   // fp32 Whh4 part: gate rows n=quad*4+r, batch col
            const float4 hv = *reinterpret_cast<const float4*>(bufH4 + (col << 2));  // h4[t-1]
#pragma unroll
            for (int r = 0; r < 4; ++r) {
                float sa = acc4[r];
                sa = fmaf(w4r[r].x, hv.x, sa);
                sa = fmaf(w4r[r].y, hv.y, sa);
                sa = fmaf(w4r[r].z, hv.z, sa);
                sa = fmaf(w4r[r].w, hv.w, sa);
                acc4[r] = sa;
            }
        }
        acc4 = MFMA(w4f0, ah0, acc4);
        acc4 = MFMA(w4f1, ah1, acc4);
        // ---- dec1[t+1] (independent of dec2[t]: both only need h3[t]) ----
        dec1_step(ah0, ah1, h1d + (((t + 1) & 1) << 10));
        // ---- dec2[t] tail: gate transpose + cell update ----
        WB();
        *reinterpret_cast<f32x4*>(gbuf + (col << 4) + (quad << 2)) = acc4;
        WB();
        {
            const float yi = gbuf[mb * 16 + u4];
            const float yf = gbuf[mb * 16 + 4 + u4];
            const float yg = gbuf[mb * 16 + 8 + u4];
            const float yo = gbuf[mb * 16 + 12 + u4];
            const float h = unitH(yi, yf, yg, yo, c4);
            out[((size_t)(b0w + mb) * TT + t) * IN + u4] = h;
            bufH4[mb * 4 + u4] = h;
        }
    }
    {   // epilogue: dec2[TT-1]
        const int t = TT - 1;
        const u16* hcur = h1d + ((t & 1) << 10);
        const bf16x8 ah0 = *reinterpret_cast<const bf16x8*>(hcur + lane * 8);
        const bf16x8 ah1 = *reinterpret_cast<const bf16x8*>(hcur + (64 + lane) * 8);
        f32x4 acc4 = bias4v;
        {
            const float4 hv = *reinterpret_cast<const float4*>(bufH4 + (col << 2));
#pragma unroll
            for (int r = 0; r < 4; ++r) {
                float sa = acc4[r];
                sa = fmaf(w4r[r].x, hv.x, sa);
                sa = fmaf(w4r[r].y, hv.y, sa);
                sa = fmaf(w4r[r].z, hv.z, sa);
                sa = fmaf(w4r[r].w, hv.w, sa);
                acc4[r] = sa;
            }
        }
        acc4 = MFMA(w4f0, ah0, acc4);
        acc4 = MFMA(w4f1, ah1, acc4);
        WB();
        *reinterpret_cast<f32x4*>(gbuf + (col << 4) + (quad << 2)) = acc4;
        WB();
        {
            const float yi = gbuf[mb * 16 + u4];
            const float yf = gbuf[mb * 16 + 4 + u4];
            const float yg = gbuf[mb * 16 + 8 + u4];
            const float yo = gbuf[mb * 16 + 12 + u4];
            const float h = unitH(yi, yf, yg, yo, c4);
            out[((size_t)(b0w + mb) * TT + t) * IN + u4] = h;
        }
    }
}

extern "C" void kernel_launch(void* const* d_in, const int* in_sizes, int n_in,
                              void* d_out, int out_size, void* d_ws, size_t ws_size,
                              hipStream_t stream) {
    (void)in_sizes; (void)n_in; (void)d_ws; (void)ws_size; (void)out_size;
    hipFuncSetAttribute(reinterpret_cast<const void*>(lstm_ae),
                        hipFuncAttributeMaxDynamicSharedMemorySize, SMEM_BYTES);
    const float* xi = (const float*)d_in[0];
    const float* w1ih = (const float*)d_in[1];
    const float* w1hh = (const float*)d_in[2];
    const float* b1i = (const float*)d_in[3];
    const float* b1h = (const float*)d_in[4];
    const float* w2ih = (const float*)d_in[5];
    const float* w2hh = (const float*)d_in[6];
    const float* b2i = (const float*)d_in[7];
    const float* b2h = (const float*)d_in[8];
    const float* w3ih = (const float*)d_in[9];
    const float* w3hh = (const float*)d_in[10];
    const float* b3i = (const float*)d_in[11];
    const float* b3h = (const float*)d_in[12];
    const float* w4ih = (const float*)d_in[13];
    const float* w4hh = (const float*)d_in[14];
    const float* b4i = (const float*)d_in[15];
    const float* b4h = (const float*)d_in[16];
    float* out = (float*)d_out;

    lstm_ae<<<dim3(BATCH / BPB), dim3(BLOCKT), SMEM_BYTES, stream>>>(
        xi, w1ih, w1hh, b1i, b1h, w2ih, w2hh, b2i, b2h,
        w3ih, w3hh, b3i, b3h, w4ih, w4hh, b4i, b4h, out);
}

// Round 4
// 296.394 us; speedup vs baseline: 1.0504x; 1.0096x over previous
//
#include <hip/hip_runtime.h>
#include <stdint.h>

// LSTM autoencoder B=32768 T=30 I=4 H=64 L=32, fp32 in/out.
// v17 = v16 (fused per-wave diagonal, 248us) + two serial-chain cuts:
//  1. Register hoist of loop-invariant fragments (VGPR budget 256 at the
//     structurally-pinned 2 waves/SIMD; v16 used 124):
//     - enc1 Wih-fold A-frags w1a[16] (64 VGPR), with BIAS folded back into
//       the MFMA (quad2 k-slots carry bias hi/lo, x-frag has 1.0 there) ->
//       removes 16 b1f b128 reads AND 16 W1C b64 reads per enc step.
//     - dec1 Wih3 frags wih3r[16] (64 VGPR) -> removes 16 b128 reads/step.
//     Enc LDS reads/step ~88->~56, dec ~50->34.
//  2. Explicit MFMA||VALU interleave: per step the MFMA bursts of the next
//     quarter are issued BEFORE the unitH tail of the previous quarter, so
//     every MFMA burst executes under an independent VALU region:
//     enc2-burst, q0-MFMA, enc2-tail, q1-MFMA, q0-tail, q2-MFMA, q1-tail,
//     q3-MFMA, q2-tail, q3-tail.  (same for dec1/dec2)
// Rationale (v16 counters): VALU 58% + MFMA 21% + ~20% LDS = pipes fully
// serialized; occupancy pinned at 2 waves/SIMD by 2048 total waves and
// 60KB weight LDS -> only intra-wave overlap + chain shortening can help.
// Math/quantization identical: 1-term bf16 h, 2-term x + 2-term bias,
// log2e folded into weights, unitH = 5 exp2 + 2 rcp.
// Layouts (HW-verified): C/D col=lane&15(batch), row=(lane>>4)*4+reg(unit)
// [m89]; A/B m|n=lane&15, k=(lane>>4)*8+j [m120].

typedef unsigned short u16;
typedef unsigned int u32;
typedef __attribute__((ext_vector_type(8))) short bf16x8;
typedef __attribute__((ext_vector_type(4))) float f32x4;
typedef __attribute__((ext_vector_type(4))) u32 u32x4;
typedef __attribute__((ext_vector_type(2))) u32 u32x2;

#define BATCH 32768
#define TT 30
#define IN 4
#define WAVES 8
#define BLOCKT (WAVES * 64)   // 512
#define MB 16
#define BPB (WAVES * MB)      // 128 batches/block -> grid 256

#define LOG2E 1.4426950408889634f
#define LOG2E2 2.8853900817779268f

// ---- LDS word (u32/float) offsets ----
// enc weights (region 0..16383)
#define O_WHH1 0        // 8192 words (32 frags)
#define O_W1C  8192     // 2048 words (256 rows x 16 u16: whi4|wlo4|bhi|blo|0..)
#define O_WIH2 10240    // 4096
#define O_WHH2 14336    // 2048 -> 16384
// dec weights (same region, restaged)
#define O_WHH3 0        // 8192
#define O_WIH3 8192     // 4096
#define O_WIH4 12288    // 512
#define O_W4HHF 12800   // 64 fp32 -> 12864
// biases (staged once, survive the restage)
#define O_B2F 16384     // 128
#define O_B3F 16512     // 256
#define O_B4F 16768     // 16
#define O_BUFS 16784
// per-wave bufs: h1/h3 DBUF 1024w (2 x 512) | h2/latent 256w | gbuf 256w | h4 64w
#define PBUF 1600
#define SMEM_WORDS (O_BUFS + WAVES * PBUF)   // 29584
#define SMEM_BYTES (SMEM_WORDS * 4)          // 118336 <= 163840

#define WB() __builtin_amdgcn_wave_barrier()
// arg order: A = weight frag, B = data frag.
#define MFMA(a, b, c) __builtin_amdgcn_mfma_f32_16x16x32_bf16((a), (b), (c), 0, 0, 0)

__device__ __forceinline__ u16 f2bf(float f) {   // RNE fp32->bf16 (staging)
    u32 u = __float_as_uint(f);
    u += 0x7fffu + ((u >> 16) & 1u);
    return (u16)(u >> 16);
}
__device__ __forceinline__ float bf2f(u16 v) { return __uint_as_float(((u32)v) << 16); }

// packed RNE fp32x2 -> bf16x2 (lo=a, hi=b)
__device__ __forceinline__ u32 cvtpk2(float a, float b) {
    u32 d;
    asm("v_cvt_pk_bf16_f32 %0, %1, %2" : "=v"(d) : "v"(a), "v"(b));
    return d;
}

// Fused LSTM cell update. Inputs pre-scaled (i,f,o by log2e; g by 2*log2e).
// Exact algebra of sig/tanh with merged reciprocals: 5 exp2 + 2 rcp.
__device__ __forceinline__ float unitH(float yi, float yf, float yg, float yo, float& c) {
    const float ei = __builtin_amdgcn_exp2f(-yi);
    const float ef = __builtin_amdgcn_exp2f(-yf);
    const float eg = __builtin_amdgcn_exp2f(yg);
    const float eo = __builtin_amdgcn_exp2f(-yo);
    const float Z = (1.f + ei) * (1.f + eg);
    const float X = 1.f + ef;
    const float num = fmaf(eg - 1.f, X, c * Z);
    c = num * __builtin_amdgcn_rcpf(X * Z);
    const float ec = __builtin_amdgcn_exp2f(c * LOG2E2);
    return (ec - 1.f) * __builtin_amdgcn_rcpf((1.f + eo) * (1.f + ec));
}

// Stage fp32 W[N][K] -> bf16 hi, operand-fragment order, rows pre-scaled by
// gate factor (gate = (n>>GS)&3; g-gate (==2) gets 2*log2e, else log2e).
template <int KT, int GS>
__device__ __forceinline__ void stageBh(u16* hi, const float* src, int N, int tid) {
    const int K = KT * 32;
    const int total = N * K;
    for (int idx = tid; idx < total; idx += BLOCKT) {
        const int j = idx & 7;
        const int l = (idx >> 3) & 63;
        const int pr = idx >> 9;
        const int kt = pr & (KT - 1);
        const int nt = pr / KT;
        const int n = (nt << 4) | (l & 15);
        const int k = (kt << 5) + ((l >> 4) << 3) + j;
        const float s = (((n >> GS) & 3) == 2) ? LOG2E2 : LOG2E;
        hi[idx] = f2bf(src[n * K + k] * s);
    }
}

// ---- enc1 quarter: 12 MFMAs into ACC[4] ----
#define ENC1_MFMA(Q, ACC, A1X, AH0, AH1)                                                   \
    _Pragma("unroll") for (int i_ = 0; i_ < 4; ++i_) {                                     \
        const int nt_ = i_ * 4 + (Q);                                                      \
        const bf16x8 bh0_ = *reinterpret_cast<const bf16x8*>(Whh1hi + ((nt_ * 2 + 0) * 64 + lane) * 8); \
        const bf16x8 bh1_ = *reinterpret_cast<const bf16x8*>(Whh1hi + ((nt_ * 2 + 1) * 64 + lane) * 8); \
        f32x4 a_ = MFMA(w1a[nt_], (A1X), zf);                                              \
        a_ = MFMA(bh0_, (AH0), a_);                                                        \
        a_ = MFMA(bh1_, (AH1), a_);                                                        \
        (ACC)[i_] = a_;                                                                    \
    }

// ---- enc1 quarter tail: 4 unitH + packed h write ----
#define ENC1_TAIL(Q, ACC, HOUT) {                                                          \
        const float h0_ = unitH((ACC)[0][0], (ACC)[1][0], (ACC)[2][0], (ACC)[3][0], c1[Q][0]); \
        const float h1_ = unitH((ACC)[0][1], (ACC)[1][1], (ACC)[2][1], (ACC)[3][1], c1[Q][1]); \
        const float h2_ = unitH((ACC)[0][2], (ACC)[1][2], (ACC)[2][2], (ACC)[3][2], c1[Q][2]); \
        const float h3_ = unitH((ACC)[0][3], (ACC)[1][3], (ACC)[2][3], (ACC)[3][3], c1[Q][3]); \
        u32x2 wv_;                                                                         \
        wv_.x = cvtpk2(h0_, h1_);                                                          \
        wv_.y = cvtpk2(h2_, h3_);                                                          \
        *reinterpret_cast<u32x2*>((HOUT) + hbase + (((Q) >> 1) << 9) + (((Q) & 1) << 8)) = wv_; \
    }

// ---- enc2: 24 MFMAs into ACC2[8] ----
#define ENC2_BURST(AH0, AH1, A2H, ACC2)                                                    \
    _Pragma("unroll") for (int nt_ = 0; nt_ < 8; ++nt_) {                                  \
        const bf16x8 bh0_ = *reinterpret_cast<const bf16x8*>(Wih2hi + ((nt_ * 2 + 0) * 64 + lane) * 8); \
        const bf16x8 bh1_ = *reinterpret_cast<const bf16x8*>(Wih2hi + ((nt_ * 2 + 1) * 64 + lane) * 8); \
        const bf16x8 ch_ = *reinterpret_cast<const bf16x8*>(Whh2hi + (nt_ * 64 + lane) * 8); \
        f32x4 a_ = b2r[nt_];                                                               \
        a_ = MFMA(bh0_, (AH0), a_);                                                        \
        a_ = MFMA(bh1_, (AH1), a_);                                                        \
        a_ = MFMA(ch_, (A2H), a_);                                                         \
        (ACC2)[nt_] = a_;                                                                  \
    }

#define ENC2_TAIL(ACC2)                                                                    \
    _Pragma("unroll") for (int q_ = 0; q_ < 2; ++q_) {                                     \
        const float h0_ = unitH((ACC2)[q_][0], (ACC2)[2 + q_][0], (ACC2)[4 + q_][0], (ACC2)[6 + q_][0], c2[q_][0]); \
        const float h1_ = unitH((ACC2)[q_][1], (ACC2)[2 + q_][1], (ACC2)[4 + q_][1], (ACC2)[6 + q_][1], c2[q_][1]); \
        const float h2_ = unitH((ACC2)[q_][2], (ACC2)[2 + q_][2], (ACC2)[4 + q_][2], (ACC2)[6 + q_][2], c2[q_][2]); \
        const float h3_ = unitH((ACC2)[q_][3], (ACC2)[2 + q_][3], (ACC2)[4 + q_][3], (ACC2)[6 + q_][3], c2[q_][3]); \
        u32x2 wv_;                                                                         \
        wv_.x = cvtpk2(h0_, h1_);                                                          \
        wv_.y = cvtpk2(h2_, h3_);                                                          \
        *reinterpret_cast<u32x2*>(h2b + hbase + (q_ << 8)) = wv_;                          \
    }

// ---- dec1 quarter: 12 MFMAs into ACC[4] ----
#define DEC1_MFMA(Q, ACC, AH0, AH1)                                                        \
    _Pragma("unroll") for (int i_ = 0; i_ < 4; ++i_) {                                     \
        const int nt_ = i_ * 4 + (Q);                                                      \
        const bf16x8 bh0_ = *reinterpret_cast<const bf16x8*>(Whh3hi + ((nt_ * 2 + 0) * 64 + lane) * 8); \
        const bf16x8 bh1_ = *reinterpret_cast<const bf16x8*>(Whh3hi + ((nt_ * 2 + 1) * 64 + lane) * 8); \
        f32x4 a_ = MFMA(wih3r[nt_], aLh, b3r[nt_]);                                        \
        a_ = MFMA(bh0_, (AH0), a_);                                                        \
        a_ = MFMA(bh1_, (AH1), a_);                                                        \
        (ACC)[i_] = a_;                                                                    \
    }

#define DEC1_TAIL(Q, ACC, HOUT) {                                                          \
        const float h0_ = unitH((ACC)[0][0], (ACC)[1][0], (ACC)[2][0], (ACC)[3][0], c3[Q][0]); \
        const float h1_ = unitH((ACC)[0][1], (ACC)[1][1], (ACC)[2][1], (ACC)[3][1], c3[Q][1]); \
        const float h2_ = unitH((ACC)[0][2], (ACC)[1][2], (ACC)[2][2], (ACC)[3][2], c3[Q][2]); \
        const float h3_ = unitH((ACC)[0][3], (ACC)[1][3], (ACC)[2][3], (ACC)[3][3], c3[Q][3]); \
        u32x2 wv_;                                                                         \
        wv_.x = cvtpk2(h0_, h1_);                                                          \
        wv_.y = cvtpk2(h2_, h3_);                                                          \
        *reinterpret_cast<u32x2*>((HOUT) + hbase + (((Q) >> 1) << 9) + (((Q) & 1) << 8)) = wv_; \
    }

__global__ __launch_bounds__(BLOCKT)
__attribute__((amdgpu_waves_per_eu(2)))
void lstm_ae(
    const float* __restrict__ x,
    const float* __restrict__ w1ih, const float* __restrict__ w1hh,
    const float* __restrict__ b1i, const float* __restrict__ b1h,
    const float* __restrict__ w2ih, const float* __restrict__ w2hh,
    const float* __restrict__ b2i, const float* __restrict__ b2h,
    const float* __restrict__ w3ih, const float* __restrict__ w3hh,
    const float* __restrict__ b3i, const float* __restrict__ b3h,
    const float* __restrict__ w4ih, const float* __restrict__ w4hh,
    const float* __restrict__ b4i, const float* __restrict__ b4h,
    float* __restrict__ out) {
    extern __shared__ float smem[];
    float* W = smem;

    const int tid = threadIdx.x;
    const int wave = tid >> 6, lane = tid & 63;
    const int col = lane & 15, quad = lane >> 4;

    float* pb = smem + O_BUFS + wave * PBUF;
    u16* h1d = (u16*)pb;            // 2048 u16: h1/h3 dbuf, parity p at p*1024
    u16* h2b = (u16*)(pb + 1024);   // 512 u16: h2 / latent
    float* gbuf = pb + 1280;        // 256 f (dec2 gate transpose)
    float* bufH4 = pb + 1536;       // 64 f (dec2 h feedback)

    const int b0w = blockIdx.x * BPB + wave * MB;
    // per-lane u16 base of this lane's 4-unit group inside a k-tile frag
    const int hbase = (col << 3) + ((quad & 1) << 2) + ((quad >> 1) << 7);

    // ---------------- stage ENCODER weights + biases ----------------
    stageBh<2, 6>((u16*)(W + O_WHH1), w1hh, 256, tid);
    stageBh<2, 5>((u16*)(W + O_WIH2), w2ih, 128, tid);
    stageBh<1, 5>((u16*)(W + O_WHH2), w2hh, 128, tid);
    {   // W1C rows (16 u16): [whi0-3 | wlo0-3 | bhi | blo | 0 x6]
        u16* C = (u16*)(W + O_W1C);
        for (int idx = tid; idx < 256 * 16; idx += BLOCKT) {
            const int n = idx >> 4, j = idx & 15;
            const float sc = ((n >> 6) == 2) ? LOG2E2 : LOG2E;
            u16 v = 0;
            if (j < 4) {
                v = f2bf(w1ih[n * 4 + j] * sc);
            } else if (j < 8) {
                const float w = w1ih[n * 4 + (j - 4)] * sc;
                v = f2bf(w - bf2f(f2bf(w)));
            } else if (j == 8) {
                v = f2bf((b1i[n] + b1h[n]) * sc);
            } else if (j == 9) {
                const float b = (b1i[n] + b1h[n]) * sc;
                v = f2bf(b - bf2f(f2bf(b)));
            }
            C[idx] = v;
        }
    }
    float* b2f = W + O_B2F;
    float* b3f = W + O_B3F;
    float* b4f = W + O_B4F;
    for (int i = tid; i < 128; i += BLOCKT)
        b2f[i] = (b2i[i] + b2h[i]) * (((i >> 5) == 2) ? LOG2E2 : LOG2E);
    for (int i = tid; i < 256; i += BLOCKT)
        b3f[i] = (b3i[i] + b3h[i]) * (((i >> 6) == 2) ? LOG2E2 : LOG2E);
    for (int i = tid; i < 16; i += BLOCKT)
        b4f[i] = (b4i[i] + b4h[i]) * (((i >> 2) == 2) ? LOG2E2 : LOG2E);
    {   // zero h2 + h4 feedback (h1/h3 prologues use reg-0 frags)
        u32* z = (u32*)pb;
        for (int i = lane; i < 256; i += 64) z[1024 + i] = 0u;
        bufH4[lane] = 0.f;
    }
    __syncthreads();

    const u16* Whh1hi = (const u16*)(W + O_WHH1);
    const u16* Wih2hi = (const u16*)(W + O_WIH2);
    const u16* Whh2hi = (const u16*)(W + O_WHH2);

    // ---- hoist enc1 fold A-frags (64 VGPR): per quad
    //   q0=[whi,whi] (k0-7: x hi|lo), q1=[wlo,wlo] (k8-11: x hi; k12-15: 0),
    //   q2=[bhi,blo,0..] (k16-17: x 1.0), q3=0
    bf16x8 w1a[16];
    {
        const u16* Cx = (const u16*)(W + O_W1C);
#pragma unroll
        for (int nt = 0; nt < 16; ++nt) {
            const u16* row = Cx + (((nt << 4) | col) << 4);
            u32x4 v = {0u, 0u, 0u, 0u};
            if (quad == 0) {
                const u32x2 p = *reinterpret_cast<const u32x2*>(row);
                v.x = p.x; v.y = p.y; v.z = p.x; v.w = p.y;
            } else if (quad == 1) {
                const u32x2 p = *reinterpret_cast<const u32x2*>(row + 4);
                v.x = p.x; v.y = p.y; v.z = p.x; v.w = p.y;
            } else if (quad == 2) {
                v.x = *reinterpret_cast<const u32*>(row + 8);
            }
            w1a[nt] = __builtin_bit_cast(bf16x8, v);
        }
    }
    // hoist enc2 bias (32 VGPR)
    f32x4 b2r[8];
#pragma unroll
    for (int nt = 0; nt < 8; ++nt)
        b2r[nt] = *reinterpret_cast<const f32x4*>(b2f + nt * 16 + (quad << 2));

    // ================= encoder (fused diagonal, interleaved) =================
    float c1[4][4];
    float c2[2][4];
#pragma unroll
    for (int q = 0; q < 4; ++q)
#pragma unroll
        for (int r = 0; r < 4; ++r) c1[q][r] = 0.f;
#pragma unroll
    for (int q = 0; q < 2; ++q)
#pragma unroll
        for (int r = 0; r < 4; ++r) c2[q][r] = 0.f;

    const f32x4 zf = {0.f, 0.f, 0.f, 0.f};
    float4 xcur = *reinterpret_cast<const float4*>(x + ((size_t)(b0w + col) * TT + 0) * IN);

    // x B-frag: quad0 [xhi,xlo], quad1 [xhi,0], quad2 [1.0 1.0 0.. (bias)], quad3 0
    auto buildX = [&](const float4 xc) -> bf16x8 {
        const u32 hi01 = cvtpk2(xc.x, xc.y);
        const u32 hi23 = cvtpk2(xc.z, xc.w);
        const float r0 = xc.x - __uint_as_float(hi01 << 16);
        const float r1 = xc.y - __uint_as_float(hi01 & 0xffff0000u);
        const float r2 = xc.z - __uint_as_float(hi23 << 16);
        const float r3 = xc.w - __uint_as_float(hi23 & 0xffff0000u);
        const u32 lo01 = cvtpk2(r0, r1);
        const u32 lo23 = cvtpk2(r2, r3);
        u32x4 xv;
        xv.x = (quad <= 1) ? hi01 : ((quad == 2) ? 0x3F803F80u : 0u);
        xv.y = (quad <= 1) ? hi23 : 0u;
        xv.z = (quad == 0) ? lo01 : 0u;
        xv.w = (quad == 0) ? lo23 : 0u;
        return __builtin_bit_cast(bf16x8, xv);
    };

    {   // prologue: enc1[0] with h1[-1] = 0 -> h1[0] at parity 0
        const bf16x8 z8 = {};
        const bf16x8 a1x = buildX(xcur);
        xcur = *reinterpret_cast<const float4*>(x + ((size_t)(b0w + col) * TT + 1) * IN);
        f32x4 accA[4], accB[4];
        ENC1_MFMA(0, accA, a1x, z8, z8)
        ENC1_MFMA(1, accB, a1x, z8, z8)
        ENC1_TAIL(0, accA, h1d)
        ENC1_MFMA(2, accA, a1x, z8, z8)
        ENC1_TAIL(1, accB, h1d)
        ENC1_MFMA(3, accB, a1x, z8, z8)
        ENC1_TAIL(2, accA, h1d)
        ENC1_TAIL(3, accB, h1d)
    }
    for (int t = 0; t < TT - 1; ++t) {
        const u16* hcur = h1d + ((t & 1) << 10);          // h1[t]
        u16* hnext = h1d + (((t + 1) & 1) << 10);         // h1[t+1]
        const bf16x8 ah0 = *reinterpret_cast<const bf16x8*>(hcur + lane * 8);
        const bf16x8 ah1 = *reinterpret_cast<const bf16x8*>(hcur + (64 + lane) * 8);
        const bf16x8 a2h = *reinterpret_cast<const bf16x8*>(h2b + lane * 8);   // h2[t-1]
        // enc2[t] MFMA burst
        f32x4 acc2[8];
        ENC2_BURST(ah0, ah1, a2h, acc2)
        // enc1[t+1] x-frag + prefetch
        const bf16x8 a1x = buildX(xcur);
        {
            const int tn = (t + 2 < TT) ? t + 2 : TT - 1;
            xcur = *reinterpret_cast<const float4*>(x + ((size_t)(b0w + col) * TT + tn) * IN);
        }
        // interleave: each MFMA burst runs under the previous tail's VALU
        f32x4 accA[4], accB[4];
        ENC1_MFMA(0, accA, a1x, ah0, ah1)
        WB();   // keep a2h read ordered before the h2b overwrite below
        ENC2_TAIL(acc2)
        ENC1_MFMA(1, accB, a1x, ah0, ah1)
        ENC1_TAIL(0, accA, hnext)
        ENC1_MFMA(2, accA, a1x, ah0, ah1)
        ENC1_TAIL(1, accB, hnext)
        ENC1_MFMA(3, accB, a1x, ah0, ah1)
        ENC1_TAIL(2, accA, hnext)
        ENC1_TAIL(3, accB, hnext)
    }
    {   // epilogue: enc2[TT-1]
        const u16* hcur = h1d + (((TT - 1) & 1) << 10);
        const bf16x8 ah0 = *reinterpret_cast<const bf16x8*>(hcur + lane * 8);
        const bf16x8 ah1 = *reinterpret_cast<const bf16x8*>(hcur + (64 + lane) * 8);
        const bf16x8 a2h = *reinterpret_cast<const bf16x8*>(h2b + lane * 8);
        f32x4 acc2[8];
        ENC2_BURST(ah0, ah1, a2h, acc2)
        WB();
        ENC2_TAIL(acc2)
    }
    // h2b holds the latent.

    // ---------------- re-stage DECODER weights ----------------
    __syncthreads();   // all waves done reading enc weights
    stageBh<2, 6>((u16*)(W + O_WHH3), w3hh, 256, tid);
    stageBh<1, 6>((u16*)(W + O_WIH3), w3ih, 256, tid);
    stageBh<2, 2>((u16*)(W + O_WIH4), w4ih, 16, tid);
    for (int i = tid; i < 64; i += BLOCKT)
        W[O_W4HHF + i] = w4hh[i] * ((((i >> 4) & 3) == 2) ? LOG2E2 : LOG2E);

    const bf16x8 aLh = *reinterpret_cast<const bf16x8*>(h2b + lane * 8);   // latent frag
    float c3[4][4];
#pragma unroll
    for (int q = 0; q < 4; ++q)
#pragma unroll
        for (int r = 0; r < 4; ++r) c3[q][r] = 0.f;
    float c4 = 0.f;
    const int u4 = lane & 3, mb = lane >> 2;
    __syncthreads();   // dec weights visible

    const u16* Whh3hi = (const u16*)(W + O_WHH3);
    const u16* Wih3hi = (const u16*)(W + O_WIH3);
    // hoist dec regs: wih3r frags (64 VGPR), b3 (64), b4 (4), Wih4 frags (8), W4hh rows (16)
    bf16x8 wih3r[16];
#pragma unroll
    for (int nt = 0; nt < 16; ++nt)
        wih3r[nt] = *reinterpret_cast<const bf16x8*>(Wih3hi + (nt * 64 + lane) * 8);
    f32x4 b3r[16];
#pragma unroll
    for (int nt = 0; nt < 16; ++nt)
        b3r[nt] = *reinterpret_cast<const f32x4*>(b3f + nt * 16 + (quad << 2));
    const f32x4 bias4v = *reinterpret_cast<const f32x4*>(b4f + (quad << 2));
    const bf16x8 w4f0 = *reinterpret_cast<const bf16x8*>((const u16*)(W + O_WIH4) + (0 * 64 + lane) * 8);
    const bf16x8 w4f1 = *reinterpret_cast<const bf16x8*>((const u16*)(W + O_WIH4) + (1 * 64 + lane) * 8);
    float4 w4r[4];
#pragma unroll
    for (int r = 0; r < 4; ++r)
        w4r[r] = *reinterpret_cast<const float4*>(W + O_W4HHF + ((quad * 4 + r) << 2));

    // ================= decoder (fused diagonal, interleaved) =================
    {   // prologue: dec1[0] with h3[-1] = 0 -> h3[0] at parity 0
        const bf16x8 z8 = {};
        f32x4 accA[4], accB[4];
        DEC1_MFMA(0, accA, z8, z8)
        DEC1_MFMA(1, accB, z8, z8)
        DEC1_TAIL(0, accA, h1d)
        DEC1_MFMA(2, accA, z8, z8)
        DEC1_TAIL(1, accB, h1d)
        DEC1_MFMA(3, accB, z8, z8)
        DEC1_TAIL(2, accA, h1d)
        DEC1_TAIL(3, accB, h1d)
    }
    for (int t = 0; t < TT - 1; ++t) {
        const u16* hcur = h1d + ((t & 1) << 10);          // h3[t]
        u16* hnext = h1d + (((t + 1) & 1) << 10);         // h3[t+1]
        const bf16x8 ah0 = *reinterpret_cast<const bf16x8*>(hcur + lane * 8);
        const bf16x8 ah1 = *reinterpret_cast<const bf16x8*>(hcur + (64 + lane) * 8);
        // ---- dec2[t] MFMA head ----
        f32x4 acc4 = bias4v;
        {   // fp32 Whh4 part: gate rows n=quad*4+r, batch col
            const float4 hv = *reinterpret_cast<const float4*>(bufH4 + (col << 2));  // h4[t-1]
#pragma unroll
            for (int r = 0; r < 4; ++r) {
                float sa = acc4[r];
                sa = fmaf(w4r[r].x, hv.x, sa);
                sa = fmaf(w4r[r].y, hv.y, sa);
                sa = fmaf(w4r[r].z, hv.z, sa);
                sa = fmaf(w4r[r].w, hv.w, sa);
                acc4[r] = sa;
            }
        }
        acc4 = MFMA(w4f0, ah0, acc4);
        acc4 = MFMA(w4f1, ah1, acc4);
        // ---- dec1[t+1] q0 (runs under dec2's MFMAs) ----
        f32x4 accA[4], accB[4];
        DEC1_MFMA(0, accA, ah0, ah1)
        // ---- dec2[t] tail: gate transpose + cell update (under q0 MFMAs) ----
        WB();
        *reinterpret_cast<f32x4*>(gbuf + (col << 4) + (quad << 2)) = acc4;
        WB();
        {
            const float yi = gbuf[mb * 16 + u4];
            const float yf = gbuf[mb * 16 + 4 + u4];
            const float yg = gbuf[mb * 16 + 8 + u4];
            const float yo = gbuf[mb * 16 + 12 + u4];
            const float h = unitH(yi, yf, yg, yo, c4);
            out[((size_t)(b0w + mb) * TT + t) * IN + u4] = h;
            bufH4[mb * 4 + u4] = h;
        }
        // ---- dec1[t+1] remaining quarters, interleaved ----
        DEC1_MFMA(1, accB, ah0, ah1)
        DEC1_TAIL(0, accA, hnext)
        DEC1_MFMA(2, accA, ah0, ah1)
        DEC1_TAIL(1, accB, hnext)
        DEC1_MFMA(3, accB, ah0, ah1)
        DEC1_TAIL(2, accA, hnext)
        DEC1_TAIL(3, accB, hnext)
    }
    {   // epilogue: dec2[TT-1]
        const int t = TT - 1;
        const u16* hcur = h1d + ((t & 1) << 10);
        const bf16x8 ah0 = *reinterpret_cast<const bf16x8*>(hcur + lane * 8);
        const bf16x8 ah1 = *reinterpret_cast<const bf16x8*>(hcur + (64 + lane) * 8);
        f32x4 acc4 = bias4v;
        {
            const float4 hv = *reinterpret_cast<const float4*>(bufH4 + (col << 2));
#pragma unroll
            for (int r = 0; r < 4; ++r) {
                float sa = acc4[r];
                sa = fmaf(w4r[r].x, hv.x, sa);
                sa = fmaf(w4r[r].y, hv.y, sa);
                sa = fmaf(w4r[r].z, hv.z, sa);
                sa = fmaf(w4r[r].w, hv.w, sa);
                acc4[r] = sa;
            }
        }
        acc4 = MFMA(w4f0, ah0, acc4);
        acc4 = MFMA(w4f1, ah1, acc4);
        WB();
        *reinterpret_cast<f32x4*>(gbuf + (col << 4) + (quad << 2)) = acc4;
        WB();
        {
            const float yi = gbuf[mb * 16 + u4];
            const float yf = gbuf[mb * 16 + 4 + u4];
            const float yg = gbuf[mb * 16 + 8 + u4];
            const float yo = gbuf[mb * 16 + 12 + u4];
            const float h = unitH(yi, yf, yg, yo, c4);
            out[((size_t)(b0w + mb) * TT + t) * IN + u4] = h;
        }
    }
}

extern "C" void kernel_launch(void* const* d_in, const int* in_sizes, int n_in,
                              void* d_out, int out_size, void* d_ws, size_t ws_size,
                              hipStream_t stream) {
    (void)in_sizes; (void)n_in; (void)d_ws; (void)ws_size; (void)out_size;
    hipFuncSetAttribute(reinterpret_cast<const void*>(lstm_ae),
                        hipFuncAttributeMaxDynamicSharedMemorySize, SMEM_BYTES);
    const float* xi = (const float*)d_in[0];
    const float* w1ih = (const float*)d_in[1];
    const float* w1hh = (const float*)d_in[2];
    const float* b1i = (const float*)d_in[3];
    const float* b1h = (const float*)d_in[4];
    const float* w2ih = (const float*)d_in[5];
    const float* w2hh = (const float*)d_in[6];
    const float* b2i = (const float*)d_in[7];
    const float* b2h = (const float*)d_in[8];
    const float* w3ih = (const float*)d_in[9];
    const float* w3hh = (const float*)d_in[10];
    const float* b3i = (const float*)d_in[11];
    const float* b3h = (const float*)d_in[12];
    const float* w4ih = (const float*)d_in[13];
    const float* w4hh = (const float*)d_in[14];
    const float* b4i = (const float*)d_in[15];
    const float* b4h = (const float*)d_in[16];
    float* out = (float*)d_out;

    lstm_ae<<<dim3(BATCH / BPB), dim3(BLOCKT), SMEM_BYTES, stream>>>(
        xi, w1ih, w1hh, b1i, b1h, w2ih, w2hh, b2i, b2h,
        w3ih, w3hh, b3i, b3h, w4ih, w4hh, b4i, b4h, out);
}